// Round 1
// baseline (4288.763 us; speedup 1.0000x reference)
//
#include <hip/hip_runtime.h>

#define BATCH  4096
#define HID    1024
#define NOUT   64
#define TSTEPS 25
#define KA2    1280   // 64 (y_prev) + 128 (static) + 1024 (h1) + 64 zero-pad -> K % 64 == 0
#define KA2R   1216   // real (non-pad) columns of layer-0 K
#define KB     2048   // 1024 (h1) + 1024 (h2)
#define LDY    1600   // TSTEPS * NOUT

typedef __attribute__((ext_vector_type(8))) __bf16 bf16x8;
typedef __attribute__((ext_vector_type(4))) float  floatx4;

__device__ __forceinline__ unsigned short f2bf(float f) {
    union { float f; unsigned u; } v; v.f = f;
    unsigned r = v.u + 0x7fffu + ((v.u >> 16) & 1u);
    return (unsigned short)(r >> 16);
}
__device__ __forceinline__ float rcpf(float x) { return __builtin_amdgcn_rcpf(x); }
__device__ __forceinline__ float sigmf(float x) { return rcpf(1.0f + __expf(-x)); }
__device__ __forceinline__ float tanh_fast(float x) {
    float ax = fabsf(x);
    float e  = __expf(-2.0f * ax);
    float t  = (1.0f - e) * rcpf(1.0f + e);
    return copysignf(t, x);
}

#define GLDS16(gp, lp) __builtin_amdgcn_global_load_lds( \
    (const __attribute__((address_space(1))) void*)(gp), \
    (__attribute__((address_space(3))) void*)(lp), 16, 0, 0)

// v8: 8-phase / counted-vmcnt schedule (T3+T4+T5+T2), replacing the 2-phase
// barrier-drain loop (which ceilings at ~900 TF / 37% MfmaUtil — measured).
//
// Geometry: 256x256 tile, BK=64, 512 thr = 8 waves (2Mx4N of 64x32 subtiles
// per C-quadrant). LDS 128 KiB = 2 buffers x {A0,A1,B0,B1} half-tiles (16 KB:
// 128 rows x 64 K bf16). Per phase: 12 ds_read_b128 + stage 1 half-tile
// (2x global_load_lds dwordx4) -> raw s_barrier -> lgkmcnt(0) -> setprio(1)
// -> 16 MFMA (one 128x128 C-quadrant x K=64) -> setprio(0) -> raw s_barrier.
// Quadrant order per K-tile: (A0,B0),(A1,B0),(A1,B1),(A0,B1).
// Stage rotation (slot freed exactly one phase earlier):
//   q0: A0(t+1) -> other buf   q1: B1(t+1) -> other buf
//   q2: B0(t+2) -> this buf    q3: A1(t+2) -> this buf, then s_waitcnt vmcnt(4)
// vmcnt(4) at q3 leaves the last 2 half-tiles (4 loads) in flight and
// guarantees everything first-used before the next q3. Never vmcnt(0) in-loop.
// LDS swizzle: 16B-chunk index kc ^= (row&7) (row stride 128 B = bank wrap)
// -> frag ds_read_b128 conflict-free; realized by pre-swizzling the per-lane
// GLOBAL source address (linear LDS dest, G21).
//
// G = X[4096,K] @ W[4096,K]^T (W rows gate-major n=gate*HID+j, block cols
// gate-interleaved nb: j=nb>>2, gate=nb&3), then per (b,j):
// gates = G + ginit[j*4+gate]; c' = sig(f)*c + sig(i)*tanh(g);
// h = sig(o)*tanh(c'); h -> d1/d2 (bf16), dfp (fp32).
__global__ __launch_bounds__(512, 2) void lstm_gate_gemm(
    const unsigned short* __restrict__ X, int K,
    const unsigned short* __restrict__ W,
    const float* __restrict__ ginit,
    float* __restrict__ cell,
    unsigned short* __restrict__ d1, int ld1, int off1,
    unsigned short* __restrict__ d2, int ld2, int off2,
    float* __restrict__ dfp)
{
    // [buf0 | buf1], each: A0 @0, A1 @16K, B0 @32K, B1 @48K (16 KB half-tiles)
    __shared__ __align__(16) char smem[131072];

    const int tid  = threadIdx.x;
    const int lane = tid & 63;
    const int w    = tid >> 6;          // 0..7
    const int ql   = lane >> 4;         // 0..3 (K-chunk group of the frag)
    const int lr   = lane & 15;
    const int wr   = w >> 2;            // 0..1: 64-row half of the quadrant's 128
    const int wc   = w & 3;             // 0..3: 32-col slice of the quadrant's 128

    // XCD-aware swizzle (8 XCDs round-robin on flat block id)
    const int id  = blockIdx.y * 16 + blockIdx.x;
    const int xcd = id & 7;
    const int c   = id >> 3;
    const int bx  = (xcd & 3) * 4 + (c & 3);
    const int by  = (xcd >> 2) * 8 + (c >> 2);
    const int m0  = bx * 256;
    const int j0  = by * 64;

    // ---- staging sources: half-tile slot s = w*128 + e*64 + lane, e in {0,1}
    // slot s holds global chunk (row = s>>3, kc = (s&7)^(row&7)).
    // e=1 is +8 rows, same kc -> src + 8*K (A) / +2*K (B, gate-interleaved).
    const int s0  = w * 128 + lane;
    const int r0  = s0 >> 3;
    const int kc0 = (s0 & 7) ^ (r0 & 7);
    const unsigned sOff = (unsigned)s0 * 16;   // LDS byte offset within region (e=1: +1024)
    const unsigned short* sA[2];
    const unsigned short* sB[2];
    sA[0] = X + (size_t)(m0 + r0) * K + kc0 * 8;
    sA[1] = X + (size_t)(m0 + 128 + r0) * K + kc0 * 8;
    {
        const int nb0 = r0, nb1 = 128 + r0;    // B rows = gate-interleaved cols
        sB[0] = W + (size_t)((nb0 & 3) * HID + j0 + (nb0 >> 2)) * K + kc0 * 8;
        sB[1] = W + (size_t)((nb1 & 3) * HID + j0 + (nb1 >> 2)) * K + kc0 * 8;
    }

#define STAGE_A(h, tt, p) do { \
    const unsigned short* _s = sA[h] + (size_t)(tt) * 64; \
    char* _d = smem + (p) * 65536 + (h) * 16384 + sOff; \
    GLDS16(_s, _d); \
    GLDS16(_s + 8 * (size_t)K, _d + 1024); \
} while (0)

#define STAGE_B(h, tt, p) do { \
    const unsigned short* _s = sB[h] + (size_t)(tt) * 64; \
    char* _d = smem + (p) * 65536 + 32768 + (h) * 16384 + sOff; \
    GLDS16(_s, _d); \
    GLDS16(_s + 2 * (size_t)K, _d + 1024); \
} while (0)

    // ---- fragment ds_read offsets (relative to half-tile base; kk=1 -> ^64)
    unsigned offA[4], offB[2];
#pragma unroll
    for (int fi = 0; fi < 4; ++fi) {
        int r = wr * 64 + fi * 16 + lr;
        offA[fi] = (unsigned)((r * 8 + (ql ^ (r & 7))) * 16);
    }
#pragma unroll
    for (int fj = 0; fj < 2; ++fj) {
        int r = wc * 32 + fj * 16 + lr;
        offB[fj] = (unsigned)(32768 + (r * 8 + (ql ^ (r & 7))) * 16);
    }

    floatx4 acc[4][4][2];   // [quadrant][fi][fj]
#pragma unroll
    for (int q = 0; q < 4; ++q)
#pragma unroll
        for (int i = 0; i < 4; ++i)
#pragma unroll
            for (int j = 0; j < 2; ++j)
                acc[q][i][j] = floatx4{0.f, 0.f, 0.f, 0.f};

    const int NT = K >> 6;   // 64-wide K-tiles (20 or 32)

    // ---- prologue: tile 0 complete + the two 2-ahead half-tiles of tile 1.
    STAGE_A(0, 0, 0); STAGE_B(0, 0, 0); STAGE_A(1, 0, 0); STAGE_B(1, 0, 0);
    STAGE_B(0, 1, 1); STAGE_A(1, 1, 1);
    asm volatile("s_waitcnt vmcnt(4)");      // tile-0 half-tiles landed
    __builtin_amdgcn_s_barrier();

#define PHASE(Q, QA, QB, STG, VM) do { \
    bf16x8 av[4][2], bv[2][2]; \
    const char* _ab = smem + cur + (QA) * 16384; \
    const char* _bb = smem + cur + (QB) * 16384; \
    _Pragma("unroll") \
    for (int fj = 0; fj < 2; ++fj) { \
        bv[fj][0] = *(const bf16x8*)(_bb + offB[fj]); \
        bv[fj][1] = *(const bf16x8*)(_bb + (offB[fj] ^ 64u)); \
    } \
    _Pragma("unroll") \
    for (int fi = 0; fi < 4; ++fi) { \
        av[fi][0] = *(const bf16x8*)(_ab + offA[fi]); \
        av[fi][1] = *(const bf16x8*)(_ab + (offA[fi] ^ 64u)); \
    } \
    STG; \
    VM; \
    __builtin_amdgcn_s_barrier(); \
    asm volatile("s_waitcnt lgkmcnt(0)"); \
    __builtin_amdgcn_sched_barrier(0); \
    __builtin_amdgcn_s_setprio(1); \
    _Pragma("unroll") \
    for (int fi = 0; fi < 4; ++fi) \
    _Pragma("unroll") \
    for (int fj = 0; fj < 2; ++fj) \
    _Pragma("unroll") \
    for (int kk = 0; kk < 2; ++kk) \
        acc[Q][fi][fj] = __builtin_amdgcn_mfma_f32_16x16x32_bf16( \
            av[fi][kk], bv[fj][kk], acc[Q][fi][fj], 0, 0, 0); \
    __builtin_amdgcn_s_setprio(0); \
    __builtin_amdgcn_s_barrier(); \
} while (0)

    int par = 0;
    for (int t = 0; t < NT; ++t) {
        const int cur = par * 65536;
        const int np  = par ^ 1;
        const int t1  = (t + 1 < NT) ? t + 1 : NT - 1;  // clamp: keeps vmcnt
        const int t2  = (t + 2 < NT) ? t + 2 : NT - 1;  // accounting uniform
        PHASE(0, 0, 0, STAGE_A(0, t1, np),  (void)0);
        PHASE(1, 1, 0, STAGE_B(1, t1, np),  (void)0);
        PHASE(2, 1, 1, STAGE_B(0, t2, par), (void)0);
        PHASE(3, 0, 1, STAGE_A(1, t2, par), asm volatile("s_waitcnt vmcnt(4)"));
        par ^= 1;
    }

    // ---- epilogue: drain stray tail DMAs before reusing LDS as scratch.
    asm volatile("s_waitcnt vmcnt(0)");
    __builtin_amdgcn_s_barrier();

    // Per-wave private scratch (2560 B), padded stride 36 floats -> float4
    // reads conflict-free. No cross-wave sharing => no barriers, only
    // intra-wave compiler fences (HW orders same-wave LDS ops).
    float* scratch = (float*)(void*)smem + w * 640;
    const int jj   = lane & 7;
    const int rsel = lane >> 3;

#pragma unroll
    for (int qd = 0; qd < 4; ++qd) {
        const int qa = (qd == 1 || qd == 2) ? 1 : 0;
        const int qb = (qd >= 2) ? 1 : 0;
        const int rowbase = m0 + qa * 128 + wr * 64;
        const int jg = j0 + qb * 32 + wc * 8 + jj;
        const float4 gi = *(const float4*)(ginit + (size_t)jg * 4);  // (i,f,g,o)
#pragma unroll
        for (int fi = 0; fi < 4; ++fi) {
            // 16x32 slab: C/D frag layout col=lane&15, row=ql*4+reg
#pragma unroll
            for (int fj = 0; fj < 2; ++fj)
#pragma unroll
                for (int r = 0; r < 4; ++r)
                    scratch[(ql * 4 + r) * 36 + fj * 16 + lr] = acc[qd][fi][fj][r];
            asm volatile("" ::: "memory");
#pragma unroll
            for (int p = 0; p < 2; ++p) {
                const int row = rsel + p * 8;
                const float4 g = *(const float4*)(scratch + row * 36 + jj * 4);
                const int b = rowbase + fi * 16 + row;
                float iv = sigmf(g.x + gi.x);
                float fv = sigmf(g.y + gi.y);
                float gv = tanh_fast(g.z + gi.z);
                float ov = sigmf(g.w + gi.w);
                size_t ci = (size_t)b * HID + jg;
                float cn = fv * cell[ci] + iv * gv;
                cell[ci] = cn;
                float hv = ov * tanh_fast(cn);
                unsigned short hb = f2bf(hv);
                d1[(size_t)b * ld1 + off1 + jg] = hb;
                if (d2)  d2[(size_t)b * ld2 + off2 + jg] = hb;
                if (dfp) dfp[(size_t)b * HID + jg] = hv;
            }
            asm volatile("" ::: "memory");
        }
    }
#undef PHASE
#undef STAGE_A
#undef STAGE_B
}

// y = h2_f32 @ Wout^T + bout (fp32); WoutT layout wt[k*64+o]; h2 staged in LDS.
__global__ __launch_bounds__(256) void out_gemm(
    const float* __restrict__ h2, const float* __restrict__ wt,
    const float* __restrict__ bout, float* __restrict__ y,
    unsigned short* __restrict__ xn)
{
    __shared__ float hl[8 * 1024];   // 32 KB: 8 h2 rows
    const int tid = threadIdx.x;
    const int b0 = blockIdx.x * 8;
#pragma unroll
    for (int r = 0; r < 8; ++r) {
        int f4 = r * 256 + tid;
        *(float4*)(hl + f4 * 4) = *(const float4*)(h2 + (size_t)b0 * 1024 + f4 * 4);
    }
    __syncthreads();
    const int o  = tid & 63;
    const int wv = tid >> 6;
    float acc0 = 0.f, acc1 = 0.f;
#pragma unroll 8
    for (int k = 0; k < 1024; ++k) {
        float wvv = wt[k * 64 + o];
        acc0 += hl[(wv * 2 + 0) * 1024 + k] * wvv;
        acc1 += hl[(wv * 2 + 1) * 1024 + k] * wvv;
    }
    float bo = bout[o];
    int b = b0 + wv * 2;
    float y0 = acc0 + bo, y1 = acc1 + bo;
    y[(size_t)b * LDY + o] = y0;
    y[(size_t)(b + 1) * LDY + o] = y1;
    xn[(size_t)b * KA2 + o] = f2bf(y0);
    xn[(size_t)(b + 1) * KA2 + o] = f2bf(y1);
}

// WoutT[k*64+o] = Wout[o*1024+k]
__global__ void build_woutT(const float* __restrict__ wout, float* __restrict__ wt)
{
    int idx = blockIdx.x * 256 + threadIdx.x;   // 65536
    int o = idx & 63, k = idx >> 6;
    wt[idx] = wout[(size_t)o * 1024 + k];
}

// interleaved bias: out[j*4+gate] = a[gate*1024+j] + b[gate*1024+j]
__global__ void build_bias(const float* __restrict__ a, const float* __restrict__ b,
                           float* __restrict__ o)
{
    int idx = blockIdx.x * 256 + threadIdx.x;   // 4096
    int gate = idx & 3, j = idx >> 2;
    int n = gate * 1024 + j;
    o[idx] = a[n] + b[n];
}

// W0[n] (KA2=1280): [0:64]=W_ih0[n][128:192] (y cols), [64:192]=W_ih0[n][0:128]
// (static cols), [192:1216]=W_hh0[n][:], [1216:1280]=0 (K%64 pad)
__global__ __launch_bounds__(256) void build_w0(
    const float* __restrict__ wih, const float* __restrict__ whh,
    unsigned short* __restrict__ w0)
{
    int idx = blockIdx.x * 256 + threadIdx.x;   // 4096*320 exact
    int n = idx / 320;
    int c = (idx - n * 320) * 4;
    float4 v = {0.f, 0.f, 0.f, 0.f};
    if (c < 64)        v = *(const float4*)(wih + (size_t)n * 192 + 128 + c);
    else if (c < 192)  v = *(const float4*)(wih + (size_t)n * 192 + (c - 64));
    else if (c < 1216) v = *(const float4*)(whh + (size_t)n * 1024 + (c - 192));
    ushort4 o;
    o.x = f2bf(v.x); o.y = f2bf(v.y); o.z = f2bf(v.z); o.w = f2bf(v.w);
    *(ushort4*)(w0 + (size_t)n * KA2 + c) = o;
}

// W1[n][0:1024] = W_ih1[n][:], W1[n][1024:2048] = W_hh1[n][:]
__global__ __launch_bounds__(256) void build_w1(
    const float* __restrict__ wih, const float* __restrict__ whh,
    unsigned short* __restrict__ w1)
{
    int idx = blockIdx.x * 256 + threadIdx.x;   // 4096*512 exact
    int n = idx >> 9;
    int c = (idx & 511) * 4;
    float4 v;
    if (c < 1024) v = *(const float4*)(wih + (size_t)n * 1024 + c);
    else          v = *(const float4*)(whh + (size_t)n * 1024 + (c - 1024));
    ushort4 o;
    o.x = f2bf(v.x); o.y = f2bf(v.y); o.z = f2bf(v.z); o.w = f2bf(v.w);
    *(ushort4*)(w1 + (size_t)n * KB + c) = o;
}

// static bf16 into X0a and X0b cols 64..191
__global__ __launch_bounds__(256) void build_x0static(
    const float* __restrict__ stat, unsigned short* __restrict__ xa,
    unsigned short* __restrict__ xb)
{
    int idx = blockIdx.x * 256 + threadIdx.x;   // 4096*32 exact
    int b = idx >> 5;
    int c = (idx & 31) * 4;
    float4 v = *(const float4*)(stat + (size_t)b * 128 + c);
    ushort4 o;
    o.x = f2bf(v.x); o.y = f2bf(v.y); o.z = f2bf(v.z); o.w = f2bf(v.w);
    *(ushort4*)(xa + (size_t)b * KA2 + 64 + c) = o;
    *(ushort4*)(xb + (size_t)b * KA2 + 64 + c) = o;
}

extern "C" void kernel_launch(void* const* d_in, const int* in_sizes, int n_in,
                              void* d_out, int out_size, void* d_ws, size_t ws_size,
                              hipStream_t stream)
{
    (void)in_sizes; (void)n_in; (void)out_size; (void)ws_size;
    const float* static_in = (const float*)d_in[0];
    const float* Wih0 = (const float*)d_in[1];
    const float* Whh0 = (const float*)d_in[2];
    const float* bih0 = (const float*)d_in[3];
    const float* bhh0 = (const float*)d_in[4];
    const float* Wih1 = (const float*)d_in[5];
    const float* Whh1 = (const float*)d_in[6];
    const float* bih1 = (const float*)d_in[7];
    const float* bhh1 = (const float*)d_in[8];
    const float* Wout = (const float*)d_in[9];
    const float* bout = (const float*)d_in[10];
    float* out = (float*)d_out;

    char* p = (char*)d_ws;
    size_t off = 0;
    auto take = [&](size_t n) { char* r = p + off; off += (n + 255) & ~(size_t)255; return r; };

    unsigned short* W0   = (unsigned short*)take((size_t)4096 * KA2 * 2);
    unsigned short* W1   = (unsigned short*)take((size_t)4096 * KB * 2);
    float*          B1b  = (float*)take(4096 * 4);
    float*          B0b  = (float*)take(4096 * 4);
    float*          WoT  = (float*)take((size_t)1024 * 64 * 4);
    float*          H2f  = (float*)take((size_t)BATCH * HID * 4);
    float*          C1   = (float*)take((size_t)BATCH * HID * 4);
    float*          C2   = (float*)take((size_t)BATCH * HID * 4);
    unsigned short* X0a  = (unsigned short*)take((size_t)BATCH * KA2 * 2);
    unsigned short* X0b  = (unsigned short*)take((size_t)BATCH * KA2 * 2);
    unsigned short* X1a  = (unsigned short*)take((size_t)BATCH * KB * 2);
    unsigned short* X1b  = (unsigned short*)take((size_t)BATCH * KB * 2);
    // total ~131 MiB

    hipMemsetAsync(C1, 0, (size_t)BATCH * HID * 4, stream);
    hipMemsetAsync(C2, 0, (size_t)BATCH * HID * 4, stream);
    hipMemsetAsync(X0a, 0, (size_t)BATCH * KA2 * 2, stream);  // y0 = h1_0 = 0, pad = 0
    hipMemsetAsync(X0b, 0, (size_t)BATCH * KA2 * 2, stream);
    hipMemsetAsync(X1a, 0, (size_t)BATCH * KB * 2, stream);   // h2_0 = 0

    build_w0<<<5120, 256, 0, stream>>>(Wih0, Whh0, W0);
    build_w1<<<8192, 256, 0, stream>>>(Wih1, Whh1, W1);
    build_woutT<<<256, 256, 0, stream>>>(Wout, WoT);
    build_bias<<<16, 256, 0, stream>>>(bih0, bhh0, B0b);
    build_bias<<<16, 256, 0, stream>>>(bih1, bhh1, B1b);
    build_x0static<<<512, 256, 0, stream>>>(static_in, X0a, X0b);

    dim3 grid(16, 16);   // 256 blocks of 512 thr = 1 per CU (128 KB LDS)
    for (int t = 0; t < TSTEPS; ++t) {
        unsigned short* X0c = (t & 1) ? X0b : X0a;
        unsigned short* X0n = (t & 1) ? X0a : X0b;
        unsigned short* X1c = (t & 1) ? X1b : X1a;
        unsigned short* X1n = (t & 1) ? X1a : X1b;
        // layer 0: gates = X0c @ W0^T + b0; h1 -> X1c[:,0:1024] and X0n[:,192:1216]
        lstm_gate_gemm<<<grid, 512, 0, stream>>>(X0c, KA2, W0, B0b, C1,
                                                 X1c, KB, 0, X0n, KA2, 192, nullptr);
        // layer 1: gates = X1c @ W1^T + b1; h2 -> X1n[:,1024:2048] + H2f
        lstm_gate_gemm<<<grid, 512, 0, stream>>>(X1c, KB, W1, B1b, C2,
                                                 X1n, KB, 1024, nullptr, 0, 0, H2f);
        // y_t = H2f @ WoutT + bout -> out[:,t,:] and X0n[:,0:64]
        out_gemm<<<512, 256, 0, stream>>>(H2f, WoT, bout, out + t * NOUT, X0n);
    }
}

// Round 2
// 3972.718 us; speedup vs baseline: 1.0796x; 1.0796x over previous
//
#include <hip/hip_runtime.h>

#define BATCH  4096
#define HID    1024
#define NOUT   64
#define TSTEPS 25
#define KA2    1280   // 64 (y_prev) + 128 (static) + 1024 (h1) + 64 zero-pad -> K % 64 == 0
#define KA2R   1216   // real (non-pad) columns of layer-0 K
#define KB     2048   // 1024 (h1) + 1024 (h2)
#define LDY    1600   // TSTEPS * NOUT

typedef __attribute__((ext_vector_type(8))) __bf16 bf16x8;
typedef __attribute__((ext_vector_type(4))) float  floatx4;

__device__ __forceinline__ unsigned short f2bf(float f) {
    union { float f; unsigned u; } v; v.f = f;
    unsigned r = v.u + 0x7fffu + ((v.u >> 16) & 1u);
    return (unsigned short)(r >> 16);
}
__device__ __forceinline__ float rcpf(float x) { return __builtin_amdgcn_rcpf(x); }
__device__ __forceinline__ float sigmf(float x) { return rcpf(1.0f + __expf(-x)); }
__device__ __forceinline__ float tanh_fast(float x) {
    float ax = fabsf(x);
    float e  = __expf(-2.0f * ax);
    float t  = (1.0f - e) * rcpf(1.0f + e);
    return copysignf(t, x);
}

#define GLDS16(gp, lp) __builtin_amdgcn_global_load_lds( \
    (const __attribute__((address_space(1))) void*)(gp), \
    (__attribute__((address_space(3))) void*)(lp), 16, 0, 0)

// v9: 8-phase counted-vmcnt schedule, REGISTER-RESIDENT operand halves.
// v8 post-mortem: phase wall was LDS-read-bound (12 ds_read_b128/wave/phase =
// 96 KB/CU/phase ~= 750-1100 cyc > 620-cyc MFMA floor) because every phase
// re-read both operand halves. Fix = m201's actual read schedule: 24 reads
// per K-tile (12/4/8/0), operands held in VGPRs across phases.
// Quadrant order: P0=(A0,B0) P1=(A0,B1) P2=(A1,B1) P3=(A1,B0).
//   bv0 (B-half0) live the whole tile, bv1 live P1-P2, av reloaded at P0/P2.
// Stage rotation (unchanged from v8, all slots freed >=1 phase before write):
//   P0: A0(t+1)->other  P1: B1(t+1)->other  P2: B0(t+2)->cur  P3: A1(t+2)->cur
//   then s_waitcnt vmcnt(4) (never 0 in-loop): leaves the 2 newest half-tiles
//   in flight, guarantees all of tile t+1 landed.
// LDS swizzle: chunk kc ^= (row&7) (row stride 128 B = bank wrap), realized by
// pre-swizzled GLOBAL source + swizzled ds_read offsets (linear LDS dest).
//
// G = X[4096,K] @ W[4096,K]^T (W rows gate-major n=gate*HID+j, block cols
// gate-interleaved nb: j=nb>>2, gate=nb&3), then per (b,j):
// gates = G + ginit[j*4+gate]; c' = sig(f)*c + sig(i)*tanh(g);
// h = sig(o)*tanh(c'); h -> d1/d2 (bf16), dfp (fp32).
__global__ __launch_bounds__(512, 2) void lstm_gate_gemm(
    const unsigned short* __restrict__ X, int K,
    const unsigned short* __restrict__ W,
    const float* __restrict__ ginit,
    float* __restrict__ cell,
    unsigned short* __restrict__ d1, int ld1, int off1,
    unsigned short* __restrict__ d2, int ld2, int off2,
    float* __restrict__ dfp)
{
    // [buf0 | buf1], each: A0 @0, A1 @16K, B0 @32K, B1 @48K (16 KB half-tiles)
    __shared__ __align__(16) char smem[131072];

    const int tid  = threadIdx.x;
    const int lane = tid & 63;
    const int w    = tid >> 6;          // 0..7
    const int ql   = lane >> 4;         // 0..3 (K-chunk group of the frag)
    const int lr   = lane & 15;
    const int wr   = w >> 2;            // 0..1: 64-row half of the quadrant's 128
    const int wc   = w & 3;             // 0..3: 32-col slice of the quadrant's 128

    // XCD-aware swizzle (8 XCDs round-robin on flat block id)
    const int id  = blockIdx.y * 16 + blockIdx.x;
    const int xcd = id & 7;
    const int c   = id >> 3;
    const int bx  = (xcd & 3) * 4 + (c & 3);
    const int by  = (xcd >> 2) * 8 + (c >> 2);
    const int m0  = bx * 256;
    const int j0  = by * 64;

    // ---- staging sources: half-tile slot s = w*128 + lane (+64 for e=1)
    // slot s holds global chunk (row = s>>3, kc = (s&7)^(row&7)).
    const int s0  = w * 128 + lane;
    const int r0  = s0 >> 3;
    const int kc0 = (s0 & 7) ^ (r0 & 7);
    const unsigned sOff = (unsigned)s0 * 16;   // LDS byte offset within region (e=1: +1024)
    const unsigned short* sA[2];
    const unsigned short* sB[2];
    sA[0] = X + (size_t)(m0 + r0) * K + kc0 * 8;
    sA[1] = X + (size_t)(m0 + 128 + r0) * K + kc0 * 8;
    {
        const int nb0 = r0, nb1 = 128 + r0;    // B rows = gate-interleaved cols
        sB[0] = W + (size_t)((nb0 & 3) * HID + j0 + (nb0 >> 2)) * K + kc0 * 8;
        sB[1] = W + (size_t)((nb1 & 3) * HID + j0 + (nb1 >> 2)) * K + kc0 * 8;
    }

#define STAGE_A(h, tt, p) do { \
    const unsigned short* _s = sA[h] + (size_t)(tt) * 64; \
    char* _d = smem + (p) * 65536 + (h) * 16384 + sOff; \
    GLDS16(_s, _d); \
    GLDS16(_s + 8 * (size_t)K, _d + 1024); \
} while (0)

#define STAGE_B(h, tt, p) do { \
    const unsigned short* _s = sB[h] + (size_t)(tt) * 64; \
    char* _d = smem + (p) * 65536 + 32768 + (h) * 16384 + sOff; \
    GLDS16(_s, _d); \
    GLDS16(_s + 2 * (size_t)K, _d + 1024); \
} while (0)

    // ---- fragment ds_read offsets (relative to half-tile base; kk=1 -> ^64)
    unsigned offA[4], offB[2];
#pragma unroll
    for (int fi = 0; fi < 4; ++fi) {
        int r = wr * 64 + fi * 16 + lr;
        offA[fi] = (unsigned)((r * 8 + (ql ^ (r & 7))) * 16);
    }
#pragma unroll
    for (int fj = 0; fj < 2; ++fj) {
        int r = wc * 32 + fj * 16 + lr;
        offB[fj] = (unsigned)(32768 + (r * 8 + (ql ^ (r & 7))) * 16);
    }

    floatx4 acc[4][4][2];   // [quadrant][fi][fj]; q: 0=(A0,B0) 1=(A0,B1) 2=(A1,B1) 3=(A1,B0)
#pragma unroll
    for (int q = 0; q < 4; ++q)
#pragma unroll
        for (int i = 0; i < 4; ++i)
#pragma unroll
            for (int j = 0; j < 2; ++j)
                acc[q][i][j] = floatx4{0.f, 0.f, 0.f, 0.f};

    const int NT = K >> 6;   // 64-wide K-tiles (20 or 32)

    // ---- prologue: tile 0 complete + the two 2-ahead half-tiles of tile 1.
    STAGE_A(0, 0, 0); STAGE_B(0, 0, 0); STAGE_A(1, 0, 0); STAGE_B(1, 0, 0);
    STAGE_B(0, 1, 1); STAGE_A(1, 1, 1);
    asm volatile("s_waitcnt vmcnt(4)");      // tile-0 half-tiles landed
    __builtin_amdgcn_s_barrier();

#define LOAD_A(AV, HALF) do { \
    const char* _ab = smem + cur + (HALF) * 16384; \
    _Pragma("unroll") \
    for (int fi = 0; fi < 4; ++fi) { \
        AV[fi][0] = *(const bf16x8*)(_ab + offA[fi]); \
        AV[fi][1] = *(const bf16x8*)(_ab + (offA[fi] ^ 64u)); \
    } \
} while (0)

#define LOAD_B(BV, HALF) do { \
    const char* _bb = smem + cur + (HALF) * 16384; \
    _Pragma("unroll") \
    for (int fj = 0; fj < 2; ++fj) { \
        BV[fj][0] = *(const bf16x8*)(_bb + offB[fj]); \
        BV[fj][1] = *(const bf16x8*)(_bb + (offB[fj] ^ 64u)); \
    } \
} while (0)

#define MFMA_PHASE(Q, AV, BV) do { \
    __builtin_amdgcn_s_barrier(); \
    asm volatile("s_waitcnt lgkmcnt(0)"); \
    __builtin_amdgcn_sched_barrier(0); \
    __builtin_amdgcn_s_setprio(1); \
    _Pragma("unroll") \
    for (int fi = 0; fi < 4; ++fi) \
    _Pragma("unroll") \
    for (int fj = 0; fj < 2; ++fj) \
    _Pragma("unroll") \
    for (int kk = 0; kk < 2; ++kk) \
        acc[Q][fi][fj] = __builtin_amdgcn_mfma_f32_16x16x32_bf16( \
            AV[fi][kk], BV[fj][kk], acc[Q][fi][fj], 0, 0, 0); \
    __builtin_amdgcn_s_setprio(0); \
    __builtin_amdgcn_s_barrier(); \
} while (0)

    int par = 0;
    for (int t = 0; t < NT; ++t) {
        const int cur = par * 65536;
        const int np  = par ^ 1;
        const int t1  = (t + 1 < NT) ? t + 1 : NT - 1;  // clamp: keeps vmcnt
        const int t2  = (t + 2 < NT) ? t + 2 : NT - 1;  // accounting uniform
        bf16x8 av[4][2], bv0[2][2], bv1[2][2];
        // phase 0: (A0,B0) — 12 ds_read_b128
        LOAD_A(av, 0); LOAD_B(bv0, 0);
        STAGE_A(0, t1, np);
        MFMA_PHASE(0, av, bv0);
        // phase 1: (A0,B1) — 4 reads (av resident)
        LOAD_B(bv1, 1);
        STAGE_B(1, t1, np);
        MFMA_PHASE(1, av, bv1);
        // phase 2: (A1,B1) — 8 reads (bv1 resident)
        LOAD_A(av, 1);
        STAGE_B(0, t2, par);
        MFMA_PHASE(2, av, bv1);
        // phase 3: (A1,B0) — 0 reads (av, bv0 resident)
        STAGE_A(1, t2, par);
        asm volatile("s_waitcnt vmcnt(4)");
        MFMA_PHASE(3, av, bv0);
        par ^= 1;
    }

    // ---- epilogue: drain stray tail DMAs before reusing LDS as scratch.
    asm volatile("s_waitcnt vmcnt(0)");
    __builtin_amdgcn_s_barrier();

    // Per-wave private scratch (2560 B), padded stride 36 floats -> float4
    // reads conflict-free. No cross-wave sharing => no barriers, only
    // intra-wave compiler fences (HW orders same-wave LDS ops).
    float* scratch = (float*)(void*)smem + w * 640;
    const int jj   = lane & 7;
    const int rsel = lane >> 3;

#pragma unroll
    for (int qd = 0; qd < 4; ++qd) {
        const int qa = (qd >= 2) ? 1 : 0;                 // A-half of quadrant qd
        const int qb = (qd == 1 || qd == 2) ? 1 : 0;      // B-half of quadrant qd
        const int rowbase = m0 + qa * 128 + wr * 64;
        const int jg = j0 + qb * 32 + wc * 8 + jj;
        const float4 gi = *(const float4*)(ginit + (size_t)jg * 4);  // (i,f,g,o)
#pragma unroll
        for (int fi = 0; fi < 4; ++fi) {
            // 16x32 slab: C/D frag layout col=lane&15, row=ql*4+reg
#pragma unroll
            for (int fj = 0; fj < 2; ++fj)
#pragma unroll
                for (int r = 0; r < 4; ++r)
                    scratch[(ql * 4 + r) * 36 + fj * 16 + lr] = acc[qd][fi][fj][r];
            asm volatile("" ::: "memory");
#pragma unroll
            for (int p = 0; p < 2; ++p) {
                const int row = rsel + p * 8;
                const float4 g = *(const float4*)(scratch + row * 36 + jj * 4);
                const int b = rowbase + fi * 16 + row;
                float iv = sigmf(g.x + gi.x);
                float fv = sigmf(g.y + gi.y);
                float gv = tanh_fast(g.z + gi.z);
                float ov = sigmf(g.w + gi.w);
                size_t ci = (size_t)b * HID + jg;
                float cn = fv * cell[ci] + iv * gv;
                cell[ci] = cn;
                float hv = ov * tanh_fast(cn);
                unsigned short hb = f2bf(hv);
                d1[(size_t)b * ld1 + off1 + jg] = hb;
                if (d2)  d2[(size_t)b * ld2 + off2 + jg] = hb;
                if (dfp) dfp[(size_t)b * HID + jg] = hv;
            }
            asm volatile("" ::: "memory");
        }
    }
#undef MFMA_PHASE
#undef LOAD_A
#undef LOAD_B
#undef STAGE_A
#undef STAGE_B
}

// y = h2_f32 @ Wout^T + bout (fp32); WoutT layout wt[k*64+o]; h2 staged in LDS.
__global__ __launch_bounds__(256) void out_gemm(
    const float* __restrict__ h2, const float* __restrict__ wt,
    const float* __restrict__ bout, float* __restrict__ y,
    unsigned short* __restrict__ xn)
{
    __shared__ float hl[8 * 1024];   // 32 KB: 8 h2 rows
    const int tid = threadIdx.x;
    const int b0 = blockIdx.x * 8;
#pragma unroll
    for (int r = 0; r < 8; ++r) {
        int f4 = r * 256 + tid;
        *(float4*)(hl + f4 * 4) = *(const float4*)(h2 + (size_t)b0 * 1024 + f4 * 4);
    }
    __syncthreads();
    const int o  = tid & 63;
    const int wv = tid >> 6;
    float acc0 = 0.f, acc1 = 0.f;
#pragma unroll 8
    for (int k = 0; k < 1024; ++k) {
        float wvv = wt[k * 64 + o];
        acc0 += hl[(wv * 2 + 0) * 1024 + k] * wvv;
        acc1 += hl[(wv * 2 + 1) * 1024 + k] * wvv;
    }
    float bo = bout[o];
    int b = b0 + wv * 2;
    float y0 = acc0 + bo, y1 = acc1 + bo;
    y[(size_t)b * LDY + o] = y0;
    y[(size_t)(b + 1) * LDY + o] = y1;
    xn[(size_t)b * KA2 + o] = f2bf(y0);
    xn[(size_t)(b + 1) * KA2 + o] = f2bf(y1);
}

// WoutT[k*64+o] = Wout[o*1024+k]
__global__ void build_woutT(const float* __restrict__ wout, float* __restrict__ wt)
{
    int idx = blockIdx.x * 256 + threadIdx.x;   // 65536
    int o = idx & 63, k = idx >> 6;
    wt[idx] = wout[(size_t)o * 1024 + k];
}

// interleaved bias: out[j*4+gate] = a[gate*1024+j] + b[gate*1024+j]
__global__ void build_bias(const float* __restrict__ a, const float* __restrict__ b,
                           float* __restrict__ o)
{
    int idx = blockIdx.x * 256 + threadIdx.x;   // 4096
    int gate = idx & 3, j = idx >> 2;
    int n = gate * 1024 + j;
    o[idx] = a[n] + b[n];
}

// W0[n] (KA2=1280): [0:64]=W_ih0[n][128:192] (y cols), [64:192]=W_ih0[n][0:128]
// (static cols), [192:1216]=W_hh0[n][:], [1216:1280]=0 (K%64 pad)
__global__ __launch_bounds__(256) void build_w0(
    const float* __restrict__ wih, const float* __restrict__ whh,
    unsigned short* __restrict__ w0)
{
    int idx = blockIdx.x * 256 + threadIdx.x;   // 4096*320 exact
    int n = idx / 320;
    int c = (idx - n * 320) * 4;
    float4 v = {0.f, 0.f, 0.f, 0.f};
    if (c < 64)        v = *(const float4*)(wih + (size_t)n * 192 + 128 + c);
    else if (c < 192)  v = *(const float4*)(wih + (size_t)n * 192 + (c - 64));
    else if (c < 1216) v = *(const float4*)(whh + (size_t)n * 1024 + (c - 192));
    ushort4 o;
    o.x = f2bf(v.x); o.y = f2bf(v.y); o.z = f2bf(v.z); o.w = f2bf(v.w);
    *(ushort4*)(w0 + (size_t)n * KA2 + c) = o;
}

// W1[n][0:1024] = W_ih1[n][:], W1[n][1024:2048] = W_hh1[n][:]
__global__ __launch_bounds__(256) void build_w1(
    const float* __restrict__ wih, const float* __restrict__ whh,
    unsigned short* __restrict__ w1)
{
    int idx = blockIdx.x * 256 + threadIdx.x;   // 4096*512 exact
    int n = idx >> 9;
    int c = (idx & 511) * 4;
    float4 v;
    if (c < 1024) v = *(const float4*)(wih + (size_t)n * 1024 + c);
    else          v = *(const float4*)(whh + (size_t)n * 1024 + (c - 1024));
    ushort4 o;
    o.x = f2bf(v.x); o.y = f2bf(v.y); o.z = f2bf(v.z); o.w = f2bf(v.w);
    *(ushort4*)(w1 + (size_t)n * KB + c) = o;
}

// static bf16 into X0a and X0b cols 64..191
__global__ __launch_bounds__(256) void build_x0static(
    const float* __restrict__ stat, unsigned short* __restrict__ xa,
    unsigned short* __restrict__ xb)
{
    int idx = blockIdx.x * 256 + threadIdx.x;   // 4096*32 exact
    int b = idx >> 5;
    int c = (idx & 31) * 4;
    float4 v = *(const float4*)(stat + (size_t)b * 128 + c);
    ushort4 o;
    o.x = f2bf(v.x); o.y = f2bf(v.y); o.z = f2bf(v.z); o.w = f2bf(v.w);
    *(ushort4*)(xa + (size_t)b * KA2 + 64 + c) = o;
    *(ushort4*)(xb + (size_t)b * KA2 + 64 + c) = o;
}

extern "C" void kernel_launch(void* const* d_in, const int* in_sizes, int n_in,
                              void* d_out, int out_size, void* d_ws, size_t ws_size,
                              hipStream_t stream)
{
    (void)in_sizes; (void)n_in; (void)out_size; (void)ws_size;
    const float* static_in = (const float*)d_in[0];
    const float* Wih0 = (const float*)d_in[1];
    const float* Whh0 = (const float*)d_in[2];
    const float* bih0 = (const float*)d_in[3];
    const float* bhh0 = (const float*)d_in[4];
    const float* Wih1 = (const float*)d_in[5];
    const float* Whh1 = (const float*)d_in[6];
    const float* bih1 = (const float*)d_in[7];
    const float* bhh1 = (const float*)d_in[8];
    const float* Wout = (const float*)d_in[9];
    const float* bout = (const float*)d_in[10];
    float* out = (float*)d_out;

    char* p = (char*)d_ws;
    size_t off = 0;
    auto take = [&](size_t n) { char* r = p + off; off += (n + 255) & ~(size_t)255; return r; };

    unsigned short* W0   = (unsigned short*)take((size_t)4096 * KA2 * 2);
    unsigned short* W1   = (unsigned short*)take((size_t)4096 * KB * 2);
    float*          B1b  = (float*)take(4096 * 4);
    float*          B0b  = (float*)take(4096 * 4);
    float*          WoT  = (float*)take((size_t)1024 * 64 * 4);
    float*          H2f  = (float*)take((size_t)BATCH * HID * 4);
    float*          C1   = (float*)take((size_t)BATCH * HID * 4);
    float*          C2   = (float*)take((size_t)BATCH * HID * 4);
    unsigned short* X0a  = (unsigned short*)take((size_t)BATCH * KA2 * 2);
    unsigned short* X0b  = (unsigned short*)take((size_t)BATCH * KA2 * 2);
    unsigned short* X1a  = (unsigned short*)take((size_t)BATCH * KB * 2);
    unsigned short* X1b  = (unsigned short*)take((size_t)BATCH * KB * 2);
    // total ~131 MiB

    hipMemsetAsync(C1, 0, (size_t)BATCH * HID * 4, stream);
    hipMemsetAsync(C2, 0, (size_t)BATCH * HID * 4, stream);
    hipMemsetAsync(X0a, 0, (size_t)BATCH * KA2 * 2, stream);  // y0 = h1_0 = 0, pad = 0
    hipMemsetAsync(X0b, 0, (size_t)BATCH * KA2 * 2, stream);
    hipMemsetAsync(X1a, 0, (size_t)BATCH * KB * 2, stream);   // h2_0 = 0

    build_w0<<<5120, 256, 0, stream>>>(Wih0, Whh0, W0);
    build_w1<<<8192, 256, 0, stream>>>(Wih1, Whh1, W1);
    build_woutT<<<256, 256, 0, stream>>>(Wout, WoT);
    build_bias<<<16, 256, 0, stream>>>(bih0, bhh0, B0b);
    build_bias<<<16, 256, 0, stream>>>(bih1, bhh1, B1b);
    build_x0static<<<512, 256, 0, stream>>>(static_in, X0a, X0b);

    dim3 grid(16, 16);   // 256 blocks of 512 thr = 1 per CU (128 KB LDS)
    for (int t = 0; t < TSTEPS; ++t) {
        unsigned short* X0c = (t & 1) ? X0b : X0a;
        unsigned short* X0n = (t & 1) ? X0a : X0b;
        unsigned short* X1c = (t & 1) ? X1b : X1a;
        unsigned short* X1n = (t & 1) ? X1a : X1b;
        // layer 0: gates = X0c @ W0^T + b0; h1 -> X1c[:,0:1024] and X0n[:,192:1216]
        lstm_gate_gemm<<<grid, 512, 0, stream>>>(X0c, KA2, W0, B0b, C1,
                                                 X1c, KB, 0, X0n, KA2, 192, nullptr);
        // layer 1: gates = X1c @ W1^T + b1; h2 -> X1n[:,1024:2048] + H2f
        lstm_gate_gemm<<<grid, 512, 0, stream>>>(X1c, KB, W1, B1b, C2,
                                                 X1n, KB, 1024, nullptr, 0, 0, H2f);
        // y_t = H2f @ WoutT + bout -> out[:,t,:] and X0n[:,0:64]
        out_gemm<<<512, 256, 0, stream>>>(H2f, WoT, bout, out + t * NOUT, X0n);
    }
}

// Round 3
// 3939.319 us; speedup vs baseline: 1.0887x; 1.0085x over previous
//
#include <hip/hip_runtime.h>

#define BATCH  4096
#define HID    1024
#define NOUT   64
#define TSTEPS 25
#define KA2    1280   // 64 (y_prev) + 128 (static) + 1024 (h1) + 64 zero-pad -> K % 64 == 0
#define KA2R   1216   // real (non-pad) columns of layer-0 K
#define KB     2048   // 1024 (h1) + 1024 (h2)
#define LDY    1600   // TSTEPS * NOUT

typedef __attribute__((ext_vector_type(8))) __bf16 bf16x8;
typedef __attribute__((ext_vector_type(4))) float  floatx4;

__device__ __forceinline__ unsigned short f2bf(float f) {
    union { float f; unsigned u; } v; v.f = f;
    unsigned r = v.u + 0x7fffu + ((v.u >> 16) & 1u);
    return (unsigned short)(r >> 16);
}
__device__ __forceinline__ float rcpf(float x) { return __builtin_amdgcn_rcpf(x); }
__device__ __forceinline__ float sigmf(float x) { return rcpf(1.0f + __expf(-x)); }
__device__ __forceinline__ float tanh_fast(float x) {
    float ax = fabsf(x);
    float e  = __expf(-2.0f * ax);
    float t  = (1.0f - e) * rcpf(1.0f + e);
    return copysignf(t, x);
}

#define GLDS16(gp, lp) __builtin_amdgcn_global_load_lds( \
    (const __attribute__((address_space(1))) void*)(gp), \
    (__attribute__((address_space(3))) void*)(lp), 16, 0, 0)

// v10: one-phase-ahead REGISTER PREFETCH on the 4-phase/tile counted-vmcnt
// schedule. v9 post-mortem: per-phase {reads -> barrier -> lgkm(0) -> MFMA}
// serialized the LDS drain with MFMA (measured wall 4875 cyc/tile vs 2483
// MFMA floor; model matched to 1%). Now each phase's fragments are read
// during the PREVIOUS phase's MFMA window; the compiler inserts counted
// lgkm waits from visible register deps.
//   reg sets (single-buffered, lifetimes audited):
//     av1(t)   read at P0(t)         (regs free after P3(t-1))
//     av0(t+1) read at P2(t)         (free after P1(t))
//     bv1(t+1) read at P3(t) pre-MFMA (free after P2(t))
//     bv0(t+1) read at P3(t) POST-MFMA (in use by Q3; only 4 reads exposed)
//   quadrants: Q0=(A0,B0) Q1=(A0,B1) Q2=(A1,B1) Q3=(A1,B0)
//   stages: P0: A0(t+1)->np  P1: B1(t+1)->np  P2: B0(t+2)->cur  P3: A1(t+2)->cur
//   vmcnt(2) at P2-top (A0(t+1) landed) and P3-top (B1(t+1) landed); never 0
//   in-loop. One s_barrier per phase (slot rewrite distances >= 3 phases).
// LDS swizzle: chunk kc ^= (row&7), pre-swizzled GLOBAL source, linear dest.
//
// G = X[4096,K] @ W[4096,K]^T (W rows gate-major n=gate*HID+j, block cols
// gate-interleaved nb: j=nb>>2, gate=nb&3), then per (b,j):
// gates = G + ginit[j*4+gate]; c' = sig(f)*c + sig(i)*tanh(g);
// h = sig(o)*tanh(c'); h -> d1/d2 (bf16), dfp (fp32).
__global__ __launch_bounds__(512, 2) void lstm_gate_gemm(
    const unsigned short* __restrict__ X, int K,
    const unsigned short* __restrict__ W,
    const float* __restrict__ ginit,
    float* __restrict__ cell,
    unsigned short* __restrict__ d1, int ld1, int off1,
    unsigned short* __restrict__ d2, int ld2, int off2,
    float* __restrict__ dfp)
{
    // [buf0 | buf1], each: A0 @0, A1 @16K, B0 @32K, B1 @48K (16 KB half-tiles)
    __shared__ __align__(16) char smem[131072];

    const int tid  = threadIdx.x;
    const int lane = tid & 63;
    const int w    = tid >> 6;          // 0..7
    const int ql   = lane >> 4;         // 0..3 (K-chunk group of the frag)
    const int lr   = lane & 15;
    const int wr   = w >> 2;            // 0..1: 64-row half of the quadrant's 128
    const int wc   = w & 3;             // 0..3: 32-col slice of the quadrant's 128

    // XCD-aware swizzle (8 XCDs round-robin on flat block id)
    const int id  = blockIdx.y * 16 + blockIdx.x;
    const int xcd = id & 7;
    const int c   = id >> 3;
    const int bx  = (xcd & 3) * 4 + (c & 3);
    const int by  = (xcd >> 2) * 8 + (c >> 2);
    const int m0  = bx * 256;
    const int j0  = by * 64;

    // ---- staging sources: half-tile slot s = w*128 + lane (+64 for e=1)
    // slot s holds global chunk (row = s>>3, kc = (s&7)^(row&7)).
    const int s0  = w * 128 + lane;
    const int r0  = s0 >> 3;
    const int kc0 = (s0 & 7) ^ (r0 & 7);
    const unsigned sOff = (unsigned)s0 * 16;   // LDS byte offset within region (e=1: +1024)
    const unsigned short* sA[2];
    const unsigned short* sB[2];
    sA[0] = X + (size_t)(m0 + r0) * K + kc0 * 8;
    sA[1] = X + (size_t)(m0 + 128 + r0) * K + kc0 * 8;
    {
        const int nb0 = r0, nb1 = 128 + r0;    // B rows = gate-interleaved cols
        sB[0] = W + (size_t)((nb0 & 3) * HID + j0 + (nb0 >> 2)) * K + kc0 * 8;
        sB[1] = W + (size_t)((nb1 & 3) * HID + j0 + (nb1 >> 2)) * K + kc0 * 8;
    }

#define STAGE_A(h, tt, p) do { \
    const unsigned short* _s = sA[h] + (size_t)(tt) * 64; \
    char* _d = smem + (p) + (h) * 16384 + sOff; \
    GLDS16(_s, _d); \
    GLDS16(_s + 8 * (size_t)K, _d + 1024); \
} while (0)

#define STAGE_B(h, tt, p) do { \
    const unsigned short* _s = sB[h] + (size_t)(tt) * 64; \
    char* _d = smem + (p) + 32768 + (h) * 16384 + sOff; \
    GLDS16(_s, _d); \
    GLDS16(_s + 2 * (size_t)K, _d + 1024); \
} while (0)

    // ---- fragment ds_read offsets (relative to half-tile base; kk=1 -> ^64)
    unsigned offA[4], offB[2];
#pragma unroll
    for (int fi = 0; fi < 4; ++fi) {
        int r = wr * 64 + fi * 16 + lr;
        offA[fi] = (unsigned)((r * 8 + (ql ^ (r & 7))) * 16);
    }
#pragma unroll
    for (int fj = 0; fj < 2; ++fj) {
        int r = wc * 32 + fj * 16 + lr;
        offB[fj] = (unsigned)(32768 + (r * 8 + (ql ^ (r & 7))) * 16);
    }

#define LOAD_A(AV, BASE) do { \
    const char* _ab = smem + (BASE); \
    _Pragma("unroll") \
    for (int fi = 0; fi < 4; ++fi) { \
        AV[fi][0] = *(const bf16x8*)(_ab + offA[fi]); \
        AV[fi][1] = *(const bf16x8*)(_ab + (offA[fi] ^ 64u)); \
    } \
} while (0)

#define LOAD_B(BV, BASE) do { \
    const char* _bb = smem + (BASE); \
    _Pragma("unroll") \
    for (int fj = 0; fj < 2; ++fj) { \
        BV[fj][0] = *(const bf16x8*)(_bb + offB[fj]); \
        BV[fj][1] = *(const bf16x8*)(_bb + (offB[fj] ^ 64u)); \
    } \
} while (0)

#define MFMA16(Q, AV, BV) do { \
    __builtin_amdgcn_s_setprio(1); \
    _Pragma("unroll") \
    for (int fi = 0; fi < 4; ++fi) \
    _Pragma("unroll") \
    for (int fj = 0; fj < 2; ++fj) \
    _Pragma("unroll") \
    for (int kk = 0; kk < 2; ++kk) \
        acc[Q][fi][fj] = __builtin_amdgcn_mfma_f32_16x16x32_bf16( \
            AV[fi][kk], BV[fj][kk], acc[Q][fi][fj], 0, 0, 0); \
    __builtin_amdgcn_s_setprio(0); \
} while (0)

    floatx4 acc[4][4][2];   // [quadrant][fi][fj]; q: 0=(A0,B0) 1=(A0,B1) 2=(A1,B1) 3=(A1,B0)
#pragma unroll
    for (int q = 0; q < 4; ++q)
#pragma unroll
        for (int i = 0; i < 4; ++i)
#pragma unroll
            for (int j = 0; j < 2; ++j)
                acc[q][i][j] = floatx4{0.f, 0.f, 0.f, 0.f};

    const int NT = K >> 6;   // 64-wide K-tiles (20 or 32)

    // persistent operand fragments (single-buffered, rotation audited above)
    bf16x8 av0[4][2], av1[4][2], bv0[2][2], bv1[2][2];

    // ---- prologue: tile0 complete -> buf0; B0(1),A1(1) -> buf1.
    STAGE_A(0, 0, 0); STAGE_B(0, 0, 0); STAGE_A(1, 0, 0); STAGE_B(1, 0, 0);
    STAGE_B(0, 1, 65536); STAGE_A(1, 1, 65536);
    asm volatile("s_waitcnt vmcnt(4)");      // tile0's 8 loads landed
    __builtin_amdgcn_s_barrier();
    __builtin_amdgcn_sched_barrier(0);
    LOAD_A(av0, 0);          // buf0.A0
    LOAD_B(bv0, 0);          // buf0.B0
    LOAD_B(bv1, 16384);      // buf0.B1
    __builtin_amdgcn_sched_barrier(0);

    int par = 0;
    for (int t = 0; t < NT; ++t) {
        const int cur = par << 16;
        const int np  = cur ^ 65536;
        const int t1  = (t + 1 < NT) ? t + 1 : NT - 1;  // clamp: keeps vmcnt
        const int t2  = (t + 2 < NT) ? t + 2 : NT - 1;  // accounting uniform
        // ---- P0: MFMA Q0 (av0 x bv0) | prefetch av1(t) | stage A0(t+1)
        __builtin_amdgcn_s_barrier();
        __builtin_amdgcn_sched_barrier(0);
        LOAD_A(av1, cur + 16384);
        STAGE_A(0, t1, np);
        __builtin_amdgcn_sched_barrier(0);
        MFMA16(0, av0, bv0);
        // ---- P1: MFMA Q1 (av0 x bv1) | stage B1(t+1)
        __builtin_amdgcn_s_barrier();
        __builtin_amdgcn_sched_barrier(0);
        STAGE_B(1, t1, np);
        __builtin_amdgcn_sched_barrier(0);
        MFMA16(1, av0, bv1);
        // ---- P2: MFMA Q2 (av1 x bv1) | prefetch av0(t+1) | stage B0(t+2)
        asm volatile("s_waitcnt vmcnt(2)");   // A0(t+1) landed
        __builtin_amdgcn_s_barrier();
        __builtin_amdgcn_sched_barrier(0);
        LOAD_A(av0, np);
        STAGE_B(0, t2, cur);
        __builtin_amdgcn_sched_barrier(0);
        MFMA16(2, av1, bv1);
        // ---- P3: MFMA Q3 (av1 x bv0) | prefetch bv1(t+1) | stage A1(t+2)
        asm volatile("s_waitcnt vmcnt(2)");   // B1(t+1) landed
        __builtin_amdgcn_s_barrier();
        __builtin_amdgcn_sched_barrier(0);
        LOAD_B(bv1, np + 16384);
        STAGE_A(1, t2, cur);
        __builtin_amdgcn_sched_barrier(0);
        MFMA16(3, av1, bv0);
        __builtin_amdgcn_sched_barrier(0);
        LOAD_B(bv0, np);     // post-MFMA: bv0 regs just freed by Q3
        par ^= 1;
    }

    // ---- epilogue: drain tail DMAs before reusing LDS as scratch.
    asm volatile("s_waitcnt vmcnt(0)");
    __builtin_amdgcn_s_barrier();

    // Per-wave private scratch (2560 B), padded stride 36 floats -> float4
    // reads conflict-free. No cross-wave sharing => no barriers, only
    // intra-wave compiler fences (HW orders same-wave LDS ops).
    float* scratch = (float*)(void*)smem + w * 640;
    const int jj   = lane & 7;
    const int rsel = lane >> 3;

#pragma unroll
    for (int qd = 0; qd < 4; ++qd) {
        const int qa = (qd >= 2) ? 1 : 0;                 // A-half of quadrant qd
        const int qb = (qd == 1 || qd == 2) ? 1 : 0;      // B-half of quadrant qd
        const int rowbase = m0 + qa * 128 + wr * 64;
        const int jg = j0 + qb * 32 + wc * 8 + jj;
        const float4 gi = *(const float4*)(ginit + (size_t)jg * 4);  // (i,f,g,o)
#pragma unroll
        for (int fi = 0; fi < 4; ++fi) {
            // 16x32 slab: C/D frag layout col=lane&15, row=ql*4+reg
#pragma unroll
            for (int fj = 0; fj < 2; ++fj)
#pragma unroll
                for (int r = 0; r < 4; ++r)
                    scratch[(ql * 4 + r) * 36 + fj * 16 + lr] = acc[qd][fi][fj][r];
            asm volatile("" ::: "memory");
#pragma unroll
            for (int p = 0; p < 2; ++p) {
                const int row = rsel + p * 8;
                const float4 g = *(const float4*)(scratch + row * 36 + jj * 4);
                const int b = rowbase + fi * 16 + row;
                float iv = sigmf(g.x + gi.x);
                float fv = sigmf(g.y + gi.y);
                float gv = tanh_fast(g.z + gi.z);
                float ov = sigmf(g.w + gi.w);
                size_t ci = (size_t)b * HID + jg;
                float cn = fv * cell[ci] + iv * gv;
                cell[ci] = cn;
                float hv = ov * tanh_fast(cn);
                unsigned short hb = f2bf(hv);
                d1[(size_t)b * ld1 + off1 + jg] = hb;
                if (d2)  d2[(size_t)b * ld2 + off2 + jg] = hb;
                if (dfp) dfp[(size_t)b * HID + jg] = hv;
            }
            asm volatile("" ::: "memory");
        }
    }
#undef MFMA16
#undef LOAD_A
#undef LOAD_B
#undef STAGE_A
#undef STAGE_B
}

// y = h2_f32 @ Wout^T + bout (fp32); WoutT layout wt[k*64+o]; h2 staged in LDS.
__global__ __launch_bounds__(256) void out_gemm(
    const float* __restrict__ h2, const float* __restrict__ wt,
    const float* __restrict__ bout, float* __restrict__ y,
    unsigned short* __restrict__ xn)
{
    __shared__ float hl[8 * 1024];   // 32 KB: 8 h2 rows
    const int tid = threadIdx.x;
    const int b0 = blockIdx.x * 8;
#pragma unroll
    for (int r = 0; r < 8; ++r) {
        int f4 = r * 256 + tid;
        *(float4*)(hl + f4 * 4) = *(const float4*)(h2 + (size_t)b0 * 1024 + f4 * 4);
    }
    __syncthreads();
    const int o  = tid & 63;
    const int wv = tid >> 6;
    float acc0 = 0.f, acc1 = 0.f;
#pragma unroll 8
    for (int k = 0; k < 1024; ++k) {
        float wvv = wt[k * 64 + o];
        acc0 += hl[(wv * 2 + 0) * 1024 + k] * wvv;
        acc1 += hl[(wv * 2 + 1) * 1024 + k] * wvv;
    }
    float bo = bout[o];
    int b = b0 + wv * 2;
    float y0 = acc0 + bo, y1 = acc1 + bo;
    y[(size_t)b * LDY + o] = y0;
    y[(size_t)(b + 1) * LDY + o] = y1;
    xn[(size_t)b * KA2 + o] = f2bf(y0);
    xn[(size_t)(b + 1) * KA2 + o] = f2bf(y1);
}

// WoutT[k*64+o] = Wout[o*1024+k]
__global__ void build_woutT(const float* __restrict__ wout, float* __restrict__ wt)
{
    int idx = blockIdx.x * 256 + threadIdx.x;   // 65536
    int o = idx & 63, k = idx >> 6;
    wt[idx] = wout[(size_t)o * 1024 + k];
}

// interleaved bias: out[j*4+gate] = a[gate*1024+j] + b[gate*1024+j]
__global__ void build_bias(const float* __restrict__ a, const float* __restrict__ b,
                           float* __restrict__ o)
{
    int idx = blockIdx.x * 256 + threadIdx.x;   // 4096
    int gate = idx & 3, j = idx >> 2;
    int n = gate * 1024 + j;
    o[idx] = a[n] + b[n];
}

// W0[n] (KA2=1280): [0:64]=W_ih0[n][128:192] (y cols), [64:192]=W_ih0[n][0:128]
// (static cols), [192:1216]=W_hh0[n][:], [1216:1280]=0 (K%64 pad)
__global__ __launch_bounds__(256) void build_w0(
    const float* __restrict__ wih, const float* __restrict__ whh,
    unsigned short* __restrict__ w0)
{
    int idx = blockIdx.x * 256 + threadIdx.x;   // 4096*320 exact
    int n = idx / 320;
    int c = (idx - n * 320) * 4;
    float4 v = {0.f, 0.f, 0.f, 0.f};
    if (c < 64)        v = *(const float4*)(wih + (size_t)n * 192 + 128 + c);
    else if (c < 192)  v = *(const float4*)(wih + (size_t)n * 192 + (c - 64));
    else if (c < 1216) v = *(const float4*)(whh + (size_t)n * 1024 + (c - 192));
    ushort4 o;
    o.x = f2bf(v.x); o.y = f2bf(v.y); o.z = f2bf(v.z); o.w = f2bf(v.w);
    *(ushort4*)(w0 + (size_t)n * KA2 + c) = o;
}

// W1[n][0:1024] = W_ih1[n][:], W1[n][1024:2048] = W_hh1[n][:]
__global__ __launch_bounds__(256) void build_w1(
    const float* __restrict__ wih, const float* __restrict__ whh,
    unsigned short* __restrict__ w1)
{
    int idx = blockIdx.x * 256 + threadIdx.x;   // 4096*512 exact
    int n = idx >> 9;
    int c = (idx & 511) * 4;
    float4 v;
    if (c < 1024) v = *(const float4*)(wih + (size_t)n * 1024 + c);
    else          v = *(const float4*)(whh + (size_t)n * 1024 + (c - 1024));
    ushort4 o;
    o.x = f2bf(v.x); o.y = f2bf(v.y); o.z = f2bf(v.z); o.w = f2bf(v.w);
    *(ushort4*)(w1 + (size_t)n * KB + c) = o;
}

// static bf16 into X0a and X0b cols 64..191
__global__ __launch_bounds__(256) void build_x0static(
    const float* __restrict__ stat, unsigned short* __restrict__ xa,
    unsigned short* __restrict__ xb)
{
    int idx = blockIdx.x * 256 + threadIdx.x;   // 4096*32 exact
    int b = idx >> 5;
    int c = (idx & 31) * 4;
    float4 v = *(const float4*)(stat + (size_t)b * 128 + c);
    ushort4 o;
    o.x = f2bf(v.x); o.y = f2bf(v.y); o.z = f2bf(v.z); o.w = f2bf(v.w);
    *(ushort4*)(xa + (size_t)b * KA2 + 64 + c) = o;
    *(ushort4*)(xb + (size_t)b * KA2 + 64 + c) = o;
}

extern "C" void kernel_launch(void* const* d_in, const int* in_sizes, int n_in,
                              void* d_out, int out_size, void* d_ws, size_t ws_size,
                              hipStream_t stream)
{
    (void)in_sizes; (void)n_in; (void)out_size; (void)ws_size;
    const float* static_in = (const float*)d_in[0];
    const float* Wih0 = (const float*)d_in[1];
    const float* Whh0 = (const float*)d_in[2];
    const float* bih0 = (const float*)d_in[3];
    const float* bhh0 = (const float*)d_in[4];
    const float* Wih1 = (const float*)d_in[5];
    const float* Whh1 = (const float*)d_in[6];
    const float* bih1 = (const float*)d_in[7];
    const float* bhh1 = (const float*)d_in[8];
    const float* Wout = (const float*)d_in[9];
    const float* bout = (const float*)d_in[10];
    float* out = (float*)d_out;

    char* p = (char*)d_ws;
    size_t off = 0;
    auto take = [&](size_t n) { char* r = p + off; off += (n + 255) & ~(size_t)255; return r; };

    unsigned short* W0   = (unsigned short*)take((size_t)4096 * KA2 * 2);
    unsigned short* W1   = (unsigned short*)take((size_t)4096 * KB * 2);
    float*          B1b  = (float*)take(4096 * 4);
    float*          B0b  = (float*)take(4096 * 4);
    float*          WoT  = (float*)take((size_t)1024 * 64 * 4);
    float*          H2f  = (float*)take((size_t)BATCH * HID * 4);
    float*          C1   = (float*)take((size_t)BATCH * HID * 4);
    float*          C2   = (float*)take((size_t)BATCH * HID * 4);
    unsigned short* X0a  = (unsigned short*)take((size_t)BATCH * KA2 * 2);
    unsigned short* X0b  = (unsigned short*)take((size_t)BATCH * KA2 * 2);
    unsigned short* X1a  = (unsigned short*)take((size_t)BATCH * KB * 2);
    unsigned short* X1b  = (unsigned short*)take((size_t)BATCH * KB * 2);
    // total ~131 MiB

    hipMemsetAsync(C1, 0, (size_t)BATCH * HID * 4, stream);
    hipMemsetAsync(C2, 0, (size_t)BATCH * HID * 4, stream);
    hipMemsetAsync(X0a, 0, (size_t)BATCH * KA2 * 2, stream);  // y0 = h1_0 = 0, pad = 0
    hipMemsetAsync(X0b, 0, (size_t)BATCH * KA2 * 2, stream);
    hipMemsetAsync(X1a, 0, (size_t)BATCH * KB * 2, stream);   // h2_0 = 0

    build_w0<<<5120, 256, 0, stream>>>(Wih0, Whh0, W0);
    build_w1<<<8192, 256, 0, stream>>>(Wih1, Whh1, W1);
    build_woutT<<<256, 256, 0, stream>>>(Wout, WoT);
    build_bias<<<16, 256, 0, stream>>>(bih0, bhh0, B0b);
    build_bias<<<16, 256, 0, stream>>>(bih1, bhh1, B1b);
    build_x0static<<<512, 256, 0, stream>>>(static_in, X0a, X0b);

    dim3 grid(16, 16);   // 256 blocks of 512 thr = 1 per CU (128 KB LDS)
    for (int t = 0; t < TSTEPS; ++t) {
        unsigned short* X0c = (t & 1) ? X0b : X0a;
        unsigned short* X0n = (t & 1) ? X0a : X0b;
        unsigned short* X1c = (t & 1) ? X1b : X1a;
        unsigned short* X1n = (t & 1) ? X1a : X1b;
        // layer 0: gates = X0c @ W0^T + b0; h1 -> X1c[:,0:1024] and X0n[:,192:1216]
        lstm_gate_gemm<<<grid, 512, 0, stream>>>(X0c, KA2, W0, B0b, C1,
                                                 X1c, KB, 0, X0n, KA2, 192, nullptr);
        // layer 1: gates = X1c @ W1^T + b1; h2 -> X1n[:,1024:2048] + H2f
        lstm_gate_gemm<<<grid, 512, 0, stream>>>(X1c, KB, W1, B1b, C2,
                                                 X1n, KB, 1024, nullptr, 0, 0, H2f);
        // y_t = H2f @ WoutT + bout -> out[:,t,:] and X0n[:,0:64]
        out_gemm<<<512, 256, 0, stream>>>(H2f, WoT, bout, out + t * NOUT, X0n);
    }
}

// Round 4
// 3654.514 us; speedup vs baseline: 1.1736x; 1.0779x over previous
//
#include <hip/hip_runtime.h>

#define BATCH  4096
#define HID    1024
#define NOUT   64
#define TSTEPS 25
#define KA2    1280   // 64 (y_prev) + 128 (static) + 1024 (h1) + 64 zero-pad -> K % 64 == 0
#define KA2R   1216   // real (non-pad) columns of layer-0 K
#define KB     2048   // 1024 (h1) + 1024 (h2)
#define LDY    1600   // TSTEPS * NOUT

typedef __attribute__((ext_vector_type(8))) __bf16 bf16x8;
typedef __attribute__((ext_vector_type(4))) float  floatx4;

__device__ __forceinline__ unsigned short f2bf(float f) {
    union { float f; unsigned u; } v; v.f = f;
    unsigned r = v.u + 0x7fffu + ((v.u >> 16) & 1u);
    return (unsigned short)(r >> 16);
}
__device__ __forceinline__ float rcpf(float x) { return __builtin_amdgcn_rcpf(x); }
__device__ __forceinline__ float sigmf(float x) { return rcpf(1.0f + __expf(-x)); }
__device__ __forceinline__ float tanh_fast(float x) {
    float ax = fabsf(x);
    float e  = __expf(-2.0f * ax);
    float t  = (1.0f - e) * rcpf(1.0f + e);
    return copysignf(t, x);
}

#define GLDS16(gp, lp) __builtin_amdgcn_global_load_lds( \
    (const __attribute__((address_space(1))) void*)(gp), \
    (__attribute__((address_space(3))) void*)(lp), 16, 0, 0)

#define SB() __builtin_amdgcn_sched_barrier(0)

// v11: 2-TILES-AHEAD staging rotation + phase-split MFMA + epilogue prefetch.
// v10 post-mortem: loop wall 4200 cyc/tile vs 2483 MFMA floor; tightest
// staging slot had only 2 phases slack (~HBM latency) -> vmcnt stalls hit all
// 8 lockstep waves. Key fact: ALL reads of tile t's buffer finish by P0(t)
// (operands are consumed one phase ahead), so tile t+2 restages the SAME
// buffer during tile t:
//   P0: B1(t+2)  P1: A1(t+2)  P2: A0(t+2)  P3: B0(t+2)   (all -> cur buf)
// Register loads (from np = other buf, one phase ahead of use):
//   P0: av1<-cur.A1(t)   P2: av0<-np.A0(t+1)
//   P3: bv1<-np.B1(t+1), post-MFMA bv0<-np.B0(t+1)
// vmcnt: ONLY two waits/tile, both vmcnt(6) (FIFO audit: steady 8 loads
// outstanding; P2-top drains {B1,A1,A0}(t+1), P3-top drains {B0}(t+1)).
// Min landing slack = 4 phases (~3300 cyc) >> 900-cyc HBM miss latency.
// Each phase: barrier -> 4 MFMA (operands old) -> loads+1 stage -> 12 MFMA,
// so the matrix pipe starts immediately at phase top.
// Epilogue: all cell/bias loads hoisted to epilogue top (operand regs dead
// after the loop -> no occupancy impact), hiding the global-load latency
// under the LDS transpose work.
__global__ __launch_bounds__(512, 2) void lstm_gate_gemm(
    const unsigned short* __restrict__ X, int K,
    const unsigned short* __restrict__ W,
    const float* __restrict__ ginit,
    float* __restrict__ cell,
    unsigned short* __restrict__ d1, int ld1, int off1,
    unsigned short* __restrict__ d2, int ld2, int off2,
    float* __restrict__ dfp)
{
    // [buf0 | buf1], each: A0 @0, A1 @16K, B0 @32K, B1 @48K (16 KB half-tiles)
    __shared__ __align__(16) char smem[131072];

    const int tid  = threadIdx.x;
    const int lane = tid & 63;
    const int w    = tid >> 6;          // 0..7
    const int ql   = lane >> 4;         // 0..3 (K-chunk group of the frag)
    const int lr   = lane & 15;
    const int wr   = w >> 2;            // 0..1: 64-row half of the quadrant's 128
    const int wc   = w & 3;             // 0..3: 32-col slice of the quadrant's 128

    // XCD-aware swizzle (8 XCDs round-robin on flat block id)
    const int id  = blockIdx.y * 16 + blockIdx.x;
    const int xcd = id & 7;
    const int c   = id >> 3;
    const int bx  = (xcd & 3) * 4 + (c & 3);
    const int by  = (xcd >> 2) * 8 + (c >> 2);
    const int m0  = bx * 256;
    const int j0  = by * 64;

    // ---- staging sources: half-tile slot s = w*128 + lane (+64 for e=1)
    // slot s holds global chunk (row = s>>3, kc = (s&7)^(row&7)).
    const int s0  = w * 128 + lane;
    const int r0  = s0 >> 3;
    const int kc0 = (s0 & 7) ^ (r0 & 7);
    const unsigned sOff = (unsigned)s0 * 16;   // LDS byte offset within region (e=1: +1024)
    const unsigned short* sA[2];
    const unsigned short* sB[2];
    sA[0] = X + (size_t)(m0 + r0) * K + kc0 * 8;
    sA[1] = X + (size_t)(m0 + 128 + r0) * K + kc0 * 8;
    {
        const int nb0 = r0, nb1 = 128 + r0;    // B rows = gate-interleaved cols
        sB[0] = W + (size_t)((nb0 & 3) * HID + j0 + (nb0 >> 2)) * K + kc0 * 8;
        sB[1] = W + (size_t)((nb1 & 3) * HID + j0 + (nb1 >> 2)) * K + kc0 * 8;
    }

#define STAGE_A(h, tt, p) do { \
    const unsigned short* _s = sA[h] + (size_t)(tt) * 64; \
    char* _d = smem + (p) + (h) * 16384 + sOff; \
    GLDS16(_s, _d); \
    GLDS16(_s + 8 * (size_t)K, _d + 1024); \
} while (0)

#define STAGE_B(h, tt, p) do { \
    const unsigned short* _s = sB[h] + (size_t)(tt) * 64; \
    char* _d = smem + (p) + 32768 + (h) * 16384 + sOff; \
    GLDS16(_s, _d); \
    GLDS16(_s + 2 * (size_t)K, _d + 1024); \
} while (0)

    // ---- fragment ds_read offsets (relative to half-tile base; kk=1 -> ^64)
    unsigned offA[4], offB[2];
#pragma unroll
    for (int fi = 0; fi < 4; ++fi) {
        int r = wr * 64 + fi * 16 + lr;
        offA[fi] = (unsigned)((r * 8 + (ql ^ (r & 7))) * 16);
    }
#pragma unroll
    for (int fj = 0; fj < 2; ++fj) {
        int r = wc * 32 + fj * 16 + lr;
        offB[fj] = (unsigned)(32768 + (r * 8 + (ql ^ (r & 7))) * 16);
    }

#define LOAD_A(AV, BASE) do { \
    const char* _ab = smem + (BASE); \
    _Pragma("unroll") \
    for (int fi = 0; fi < 4; ++fi) { \
        AV[fi][0] = *(const bf16x8*)(_ab + offA[fi]); \
        AV[fi][1] = *(const bf16x8*)(_ab + (offA[fi] ^ 64u)); \
    } \
} while (0)

#define LOAD_B(BV, BASE) do { \
    const char* _bb = smem + (BASE); \
    _Pragma("unroll") \
    for (int fj = 0; fj < 2; ++fj) { \
        BV[fj][0] = *(const bf16x8*)(_bb + offB[fj]); \
        BV[fj][1] = *(const bf16x8*)(_bb + (offB[fj] ^ 64u)); \
    } \
} while (0)

// MFMA over fi in [F0,F1): F0=0,F1=1 -> 4 MFMA; F0=1,F1=4 -> 12 MFMA
#define MFMA_PART(Q, AV, BV, F0, F1) do { \
    __builtin_amdgcn_s_setprio(1); \
    _Pragma("unroll") \
    for (int fi = (F0); fi < (F1); ++fi) \
    _Pragma("unroll") \
    for (int fj = 0; fj < 2; ++fj) \
    _Pragma("unroll") \
    for (int kk = 0; kk < 2; ++kk) \
        acc[Q][fi][fj] = __builtin_amdgcn_mfma_f32_16x16x32_bf16( \
            AV[fi][kk], BV[fj][kk], acc[Q][fi][fj], 0, 0, 0); \
    __builtin_amdgcn_s_setprio(0); \
} while (0)

    floatx4 acc[4][4][2];   // [quadrant][fi][fj]; q: 0=(A0,B0) 1=(A0,B1) 2=(A1,B1) 3=(A1,B0)
#pragma unroll
    for (int q = 0; q < 4; ++q)
#pragma unroll
        for (int i = 0; i < 4; ++i)
#pragma unroll
            for (int j = 0; j < 2; ++j)
                acc[q][i][j] = floatx4{0.f, 0.f, 0.f, 0.f};

    const int NT = K >> 6;   // 64-wide K-tiles (20 or 32)

    bf16x8 av0[4][2], av1[4][2], bv0[2][2], bv1[2][2];

    // ---- prologue: stage tile0 -> buf0 (oldest in FIFO), tile1 -> buf1.
    STAGE_B(1, 0, 0); STAGE_A(1, 0, 0); STAGE_A(0, 0, 0); STAGE_B(0, 0, 0);
    STAGE_B(1, 1, 65536); STAGE_A(1, 1, 65536); STAGE_A(0, 1, 65536); STAGE_B(0, 1, 65536);
    asm volatile("s_waitcnt vmcnt(8)");      // tile0's 8 loads landed; tile1 in flight
    __builtin_amdgcn_s_barrier();
    SB();
    LOAD_A(av0, 0);          // buf0.A0(0)
    LOAD_B(bv0, 0);          // buf0.B0(0)
    LOAD_B(bv1, 16384);      // buf0.B1(0)
    SB();

    int par = 0;
    for (int t = 0; t < NT; ++t) {
        const int cur = par << 16;
        const int np  = cur ^ 65536;
        const int t2  = (t + 2 < NT) ? t + 2 : NT - 1;  // clamp: keeps vmcnt uniform
        // ---- P0: Q0 (av0 x bv0) | av1 <- cur.A1(t) | stage B1(t+2)->cur
        __builtin_amdgcn_s_barrier();
        SB();
        MFMA_PART(0, av0, bv0, 0, 1);
        SB();
        LOAD_A(av1, cur + 16384);
        STAGE_B(1, t2, cur);
        SB();
        MFMA_PART(0, av0, bv0, 1, 4);
        SB();
        // ---- P1: Q1 (av0 x bv1) | stage A1(t+2)->cur
        __builtin_amdgcn_s_barrier();
        SB();
        MFMA_PART(1, av0, bv1, 0, 1);
        SB();
        STAGE_A(1, t2, cur);
        SB();
        MFMA_PART(1, av0, bv1, 1, 4);
        SB();
        // ---- P2: Q2 (av1 x bv1) | av0 <- np.A0(t+1) | stage A0(t+2)->cur
        asm volatile("s_waitcnt vmcnt(6)");   // drains {B1,A1,A0}(t+1)
        __builtin_amdgcn_s_barrier();
        SB();
        MFMA_PART(2, av1, bv1, 0, 1);
        SB();
        LOAD_A(av0, np);
        STAGE_A(0, t2, cur);
        SB();
        MFMA_PART(2, av1, bv1, 1, 4);
        SB();
        // ---- P3: Q3 (av1 x bv0) | bv1 <- np.B1(t+1) | stage B0(t+2)->cur
        asm volatile("s_waitcnt vmcnt(6)");   // drains {B0}(t+1)
        __builtin_amdgcn_s_barrier();
        SB();
        MFMA_PART(3, av1, bv0, 0, 1);
        SB();
        LOAD_B(bv1, np + 16384);
        STAGE_B(0, t2, cur);
        SB();
        MFMA_PART(3, av1, bv0, 1, 4);
        SB();
        LOAD_B(bv0, np);     // bv0 regs freed by Q3; B0(t+1) landed (P3-top wait)
        par ^= 1;
    }

    // ---- epilogue: drain tail DMAs before reusing LDS as scratch.
    asm volatile("s_waitcnt vmcnt(0)");
    __builtin_amdgcn_s_barrier();

    // Per-wave private scratch (2560 B), padded stride 36 floats -> float4
    // reads conflict-free. No cross-wave sharing => no barriers, only
    // intra-wave compiler fences (HW orders same-wave LDS ops).
    float* scratch = (float*)(void*)smem + w * 640;
    const int jj   = lane & 7;
    const int rsel = lane >> 3;

    // Hoisted epilogue prefetch: cell + bias. Operand VGPRs are dead here, so
    // this reuses the loop's register budget; loads for qd>=1 hide under qd=0.
    float  cpre[4][4][2];
    float4 gi4[4];
#pragma unroll
    for (int qd = 0; qd < 4; ++qd) {
        const int qa = (qd >= 2) ? 1 : 0;
        const int qb = (qd == 1 || qd == 2) ? 1 : 0;
        const int rowbase = m0 + qa * 128 + wr * 64;
        const int jg = j0 + qb * 32 + wc * 8 + jj;
        gi4[qd] = *(const float4*)(ginit + (size_t)jg * 4);
#pragma unroll
        for (int fi = 0; fi < 4; ++fi)
#pragma unroll
            for (int p = 0; p < 2; ++p)
                cpre[qd][fi][p] = cell[(size_t)(rowbase + fi * 16 + rsel + p * 8) * HID + jg];
    }

#pragma unroll
    for (int qd = 0; qd < 4; ++qd) {
        const int qa = (qd >= 2) ? 1 : 0;                 // A-half of quadrant qd
        const int qb = (qd == 1 || qd == 2) ? 1 : 0;      // B-half of quadrant qd
        const int rowbase = m0 + qa * 128 + wr * 64;
        const int jg = j0 + qb * 32 + wc * 8 + jj;
        const float4 gi = gi4[qd];                        // (i,f,g,o)
#pragma unroll
        for (int fi = 0; fi < 4; ++fi) {
            // 16x32 slab: C/D frag layout col=lane&15, row=ql*4+reg
#pragma unroll
            for (int fj = 0; fj < 2; ++fj)
#pragma unroll
                for (int r = 0; r < 4; ++r)
                    scratch[(ql * 4 + r) * 36 + fj * 16 + lr] = acc[qd][fi][fj][r];
            asm volatile("" ::: "memory");
#pragma unroll
            for (int p = 0; p < 2; ++p) {
                const int row = rsel + p * 8;
                const float4 g = *(const float4*)(scratch + row * 36 + jj * 4);
                const int b = rowbase + fi * 16 + row;
                float iv = sigmf(g.x + gi.x);
                float fv = sigmf(g.y + gi.y);
                float gv = tanh_fast(g.z + gi.z);
                float ov = sigmf(g.w + gi.w);
                size_t ci = (size_t)b * HID + jg;
                float cn = fv * cpre[qd][fi][p] + iv * gv;
                cell[ci] = cn;
                float hv = ov * tanh_fast(cn);
                unsigned short hb = f2bf(hv);
                d1[(size_t)b * ld1 + off1 + jg] = hb;
                if (d2)  d2[(size_t)b * ld2 + off2 + jg] = hb;
                if (dfp) dfp[(size_t)b * HID + jg] = hv;
            }
            asm volatile("" ::: "memory");
        }
    }
#undef MFMA_PART
#undef LOAD_A
#undef LOAD_B
#undef STAGE_A
#undef STAGE_B
}

// y = h2_f32 @ Wout^T + bout (fp32); WoutT layout wt[k*64+o]; h2 staged in LDS.
// 16 rows/block (256 blocks = 1/CU): halves device-wide WoT re-read traffic.
__global__ __launch_bounds__(256) void out_gemm(
    const float* __restrict__ h2, const float* __restrict__ wt,
    const float* __restrict__ bout, float* __restrict__ y,
    unsigned short* __restrict__ xn)
{
    __shared__ float hl[16 * 1024];   // 64 KB: 16 h2 rows
    const int tid = threadIdx.x;
    const int b0 = blockIdx.x * 16;
#pragma unroll
    for (int r = 0; r < 16; ++r) {
        int f4 = r * 256 + tid;
        *(float4*)(hl + f4 * 4) = *(const float4*)(h2 + (size_t)b0 * 1024 + f4 * 4);
    }
    __syncthreads();
    const int o  = tid & 63;
    const int wv = tid >> 6;          // 0..3, 4 rows each
    float a0 = 0.f, a1 = 0.f, a2 = 0.f, a3 = 0.f;
#pragma unroll 8
    for (int k = 0; k < 1024; ++k) {
        float wvv = wt[k * 64 + o];
        const float* hr = hl + (wv * 4) * 1024 + k;
        a0 += hr[0]    * wvv;
        a1 += hr[1024] * wvv;
        a2 += hr[2048] * wvv;
        a3 += hr[3072] * wvv;
    }
    float bo = bout[o];
    int b = b0 + wv * 4;
    float yv[4] = {a0 + bo, a1 + bo, a2 + bo, a3 + bo};
#pragma unroll
    for (int r = 0; r < 4; ++r) {
        y[(size_t)(b + r) * LDY + o] = yv[r];
        xn[(size_t)(b + r) * KA2 + o] = f2bf(yv[r]);
    }
}

// WoutT[k*64+o] = Wout[o*1024+k]
__global__ void build_woutT(const float* __restrict__ wout, float* __restrict__ wt)
{
    int idx = blockIdx.x * 256 + threadIdx.x;   // 65536
    int o = idx & 63, k = idx >> 6;
    wt[idx] = wout[(size_t)o * 1024 + k];
}

// interleaved bias: out[j*4+gate] = a[gate*1024+j] + b[gate*1024+j]
__global__ void build_bias(const float* __restrict__ a, const float* __restrict__ b,
                           float* __restrict__ o)
{
    int idx = blockIdx.x * 256 + threadIdx.x;   // 4096
    int gate = idx & 3, j = idx >> 2;
    int n = gate * 1024 + j;
    o[idx] = a[n] + b[n];
}

// W0[n] (KA2=1280): [0:64]=W_ih0[n][128:192] (y cols), [64:192]=W_ih0[n][0:128]
// (static cols), [192:1216]=W_hh0[n][:], [1216:1280]=0 (K%64 pad)
__global__ __launch_bounds__(256) void build_w0(
    const float* __restrict__ wih, const float* __restrict__ whh,
    unsigned short* __restrict__ w0)
{
    int idx = blockIdx.x * 256 + threadIdx.x;   // 4096*320 exact
    int n = idx / 320;
    int c = (idx - n * 320) * 4;
    float4 v = {0.f, 0.f, 0.f, 0.f};
    if (c < 64)        v = *(const float4*)(wih + (size_t)n * 192 + 128 + c);
    else if (c < 192)  v = *(const float4*)(wih + (size_t)n * 192 + (c - 64));
    else if (c < 1216) v = *(const float4*)(whh + (size_t)n * 1024 + (c - 192));
    ushort4 o;
    o.x = f2bf(v.x); o.y = f2bf(v.y); o.z = f2bf(v.z); o.w = f2bf(v.w);
    *(ushort4*)(w0 + (size_t)n * KA2 + c) = o;
}

// W1[n][0:1024] = W_ih1[n][:], W1[n][1024:2048] = W_hh1[n][:]
__global__ __launch_bounds__(256) void build_w1(
    const float* __restrict__ wih, const float* __restrict__ whh,
    unsigned short* __restrict__ w1)
{
    int idx = blockIdx.x * 256 + threadIdx.x;   // 4096*512 exact
    int n = idx >> 9;
    int c = (idx & 511) * 4;
    float4 v;
    if (c < 1024) v = *(const float4*)(wih + (size_t)n * 1024 + c);
    else          v = *(const float4*)(whh + (size_t)n * 1024 + (c - 1024));
    ushort4 o;
    o.x = f2bf(v.x); o.y = f2bf(v.y); o.z = f2bf(v.z); o.w = f2bf(v.w);
    *(ushort4*)(w1 + (size_t)n * KB + c) = o;
}

// static bf16 into X0a and X0b cols 64..191
__global__ __launch_bounds__(256) void build_x0static(
    const float* __restrict__ stat, unsigned short* __restrict__ xa,
    unsigned short* __restrict__ xb)
{
    int idx = blockIdx.x * 256 + threadIdx.x;   // 4096*32 exact
    int b = idx >> 5;
    int c = (idx & 31) * 4;
    float4 v = *(const float4*)(stat + (size_t)b * 128 + c);
    ushort4 o;
    o.x = f2bf(v.x); o.y = f2bf(v.y); o.z = f2bf(v.z); o.w = f2bf(v.w);
    *(ushort4*)(xa + (size_t)b * KA2 + 64 + c) = o;
    *(ushort4*)(xb + (size_t)b * KA2 + 64 + c) = o;
}

extern "C" void kernel_launch(void* const* d_in, const int* in_sizes, int n_in,
                              void* d_out, int out_size, void* d_ws, size_t ws_size,
                              hipStream_t stream)
{
    (void)in_sizes; (void)n_in; (void)out_size; (void)ws_size;
    const float* static_in = (const float*)d_in[0];
    const float* Wih0 = (const float*)d_in[1];
    const float* Whh0 = (const float*)d_in[2];
    const float* bih0 = (const float*)d_in[3];
    const float* bhh0 = (const float*)d_in[4];
    const float* Wih1 = (const float*)d_in[5];
    const float* Whh1 = (const float*)d_in[6];
    const float* bih1 = (const float*)d_in[7];
    const float* bhh1 = (const float*)d_in[8];
    const float* Wout = (const float*)d_in[9];
    const float* bout = (const float*)d_in[10];
    float* out = (float*)d_out;

    char* p = (char*)d_ws;
    size_t off = 0;
    auto take = [&](size_t n) { char* r = p + off; off += (n + 255) & ~(size_t)255; return r; };

    unsigned short* W0   = (unsigned short*)take((size_t)4096 * KA2 * 2);
    unsigned short* W1   = (unsigned short*)take((size_t)4096 * KB * 2);
    float*          B1b  = (float*)take(4096 * 4);
    float*          B0b  = (float*)take(4096 * 4);
    float*          WoT  = (float*)take((size_t)1024 * 64 * 4);
    float*          H2f  = (float*)take((size_t)BATCH * HID * 4);
    float*          C1   = (float*)take((size_t)BATCH * HID * 4);
    float*          C2   = (float*)take((size_t)BATCH * HID * 4);
    unsigned short* X0a  = (unsigned short*)take((size_t)BATCH * KA2 * 2);
    unsigned short* X0b  = (unsigned short*)take((size_t)BATCH * KA2 * 2);
    unsigned short* X1a  = (unsigned short*)take((size_t)BATCH * KB * 2);
    unsigned short* X1b  = (unsigned short*)take((size_t)BATCH * KB * 2);
    // total ~131 MiB

    hipMemsetAsync(C1, 0, (size_t)BATCH * HID * 4, stream);
    hipMemsetAsync(C2, 0, (size_t)BATCH * HID * 4, stream);
    hipMemsetAsync(X0a, 0, (size_t)BATCH * KA2 * 2, stream);  // y0 = h1_0 = 0, pad = 0
    hipMemsetAsync(X0b, 0, (size_t)BATCH * KA2 * 2, stream);
    hipMemsetAsync(X1a, 0, (size_t)BATCH * KB * 2, stream);   // h2_0 = 0

    build_w0<<<5120, 256, 0, stream>>>(Wih0, Whh0, W0);
    build_w1<<<8192, 256, 0, stream>>>(Wih1, Whh1, W1);
    build_woutT<<<256, 256, 0, stream>>>(Wout, WoT);
    build_bias<<<16, 256, 0, stream>>>(bih0, bhh0, B0b);
    build_bias<<<16, 256, 0, stream>>>(bih1, bhh1, B1b);
    build_x0static<<<512, 256, 0, stream>>>(static_in, X0a, X0b);

    dim3 grid(16, 16);   // 256 blocks of 512 thr = 1 per CU (128 KB LDS)
    for (int t = 0; t < TSTEPS; ++t) {
        unsigned short* X0c = (t & 1) ? X0b : X0a;
        unsigned short* X0n = (t & 1) ? X0a : X0b;
        unsigned short* X1c = (t & 1) ? X1b : X1a;
        unsigned short* X1n = (t & 1) ? X1a : X1b;
        // layer 0: gates = X0c @ W0^T + b0; h1 -> X1c[:,0:1024] and X0n[:,192:1216]
        lstm_gate_gemm<<<grid, 512, 0, stream>>>(X0c, KA2, W0, B0b, C1,
                                                 X1c, KB, 0, X0n, KA2, 192, nullptr);
        // layer 1: gates = X1c @ W1^T + b1; h2 -> X1n[:,1024:2048] + H2f
        lstm_gate_gemm<<<grid, 512, 0, stream>>>(X1c, KB, W1, B1b, C2,
                                                 X1n, KB, 1024, nullptr, 0, 0, H2f);
        // y_t = H2f @ WoutT + bout -> out[:,t,:] and X0n[:,0:64]
        out_gemm<<<256, 256, 0, stream>>>(H2f, WoT, bout, out + t * NOUT, X0n);
    }
}